// Round 6
// baseline (240.203 us; speedup 1.0000x reference)
//
#include <hip/hip_runtime.h>
#include <math.h>

#define HIDDEN   2048
#define NEXPERT  64
#define TOPK     8
#define NTOK     16384
#define TOKB     64          // tokens per block (four 16-row M tiles)
#define RSQRT_H  0.02209708691207961
#define WSCALE   64.0f       // keeps f16 Wl split in normal range; undone in epilogue

typedef __attribute__((ext_vector_type(8))) _Float16       v8h;
typedef __attribute__((ext_vector_type(8))) unsigned short v8u;
typedef __attribute__((ext_vector_type(4))) float          v4f;

static __device__ __forceinline__ unsigned short f16b(float x) {
    return __builtin_bit_cast(unsigned short, (_Float16)x);   // v_cvt_f16_f32 (RNE)
}
static __device__ __forceinline__ float f16f(unsigned short u) {
    return (float)__builtin_bit_cast(_Float16, u);
}

// Weight prep into B-fragment order: wf[ks(64)][nt(4)][hl(2)][lane(64)][j(8)] f16.
// B[k][n]: n = nt*16 + (lane&15), k = ks*32 + (lane>>4)*8 + j.  v = w*scale*64.
// Also zeroes out_c (replaces a separate hipMemsetAsync dispatch).
__global__ __launch_bounds__(256) void prep_wf(
    const float* __restrict__ w, const float* __restrict__ scale,
    unsigned short* __restrict__ wf, float* __restrict__ out_c)
{
    int i    = blockIdx.x * 256 + threadIdx.x;   // 131072
    if (i < NEXPERT) out_c[i] = 0.f;
    int j    = i & 7;
    int lane = (i >> 3) & 63;
    int nt   = (i >> 9) & 3;
    int ks   = i >> 11;
    int e    = nt * 16 + (lane & 15);
    int k    = ks * 32 + (lane >> 4) * 8 + j;
    float v  = w[e * HIDDEN + k] * scale[k] * WSCALE;
    unsigned short vh = f16b(v);
    unsigned short vl = f16b(v - f16f(vh));      // Dekker split: v - hi exact in f32
    size_t base = (((size_t)(ks * 4 + nt) * 2) * 64 + lane) * 8 + j;
    wf[base]       = vh;                          // hl=0
    wf[base + 512] = vl;                          // hl=1 (stride 64*8)
}

// Convert 8 f32 -> split-f16 hi/lo fragments; accumulate sum of squares.
static __device__ __forceinline__ void cvt8(
    float4 a, float4 b, v8h& ah, v8h& al, float& ss)
{
    float vv[8] = {a.x, a.y, a.z, a.w, b.x, b.y, b.z, b.w};
    v8u uh, ul;
#pragma unroll
    for (int j = 0; j < 8; ++j) {
        float v = vv[j];
        unsigned short hh = f16b(v);
        uh[j] = hh;
        ul[j] = f16b(v - f16f(hh));   // exact residual in f32, then RNE
        ss    = fmaf(v, v, ss);
    }
    ah = __builtin_bit_cast(v8h, uh);
    al = __builtin_bit_cast(v8h, ul);
}

// 64 tokens/block, 512 thr (8 waves), grid = 256 = 1 block/CU. Wave w owns
// k-range [w*256, w*256+256) for all 64 tokens. R4/R5 spilled ~60 arch VGPRs
// (compiler pins arch side at 128; WRITE_SIZE showed 48 MB scratch). R6 fits
// under 128 arch regs:
//  - X staged via global_load_lds into per-wave-private double-buffered LDS
//    (zero destination VGPRs, no k-loop barriers, counted vmcnt(16));
//    global source pre-swizzled (group ^ (row&7)) so linear LDS writes give
//    conflict-free ds_read_b128 fragment reads (2 lanes/bank = free).
//  - B fragments double-buffered in two register sets (static ping-pong),
//    prefetched one k-step ahead -> a full 48-MFMA step of latency cover.
// logits_raw = Xh*Wh + Xh*Wl + Xl*Wh  (split-f16, per-acc order == R4/R5).
__global__ __launch_bounds__(512, 1) void router_main(
    const float* __restrict__ h, const unsigned short* __restrict__ wf,
    const float* __restrict__ pes,
    float* __restrict__ out_w, float* __restrict__ out_i, float* __restrict__ out_c)
{
    // [0,131072): stage, 8 waves x 2 bufs x 8KB   (k-loop)
    // [0,135168): lg[8][64][66] f32               (epilogue, aliases stage)
    // [135168,137216): lss[8][64]   [137216,137472): hist[64]
    __shared__ __align__(16) char smem[137472];
    float* stage = (float*)smem;
    float* lg    = (float*)smem;
    float* lss   = (float*)(smem + 135168);
    int*   hist  = (int*)(smem + 137216);

    const int tid  = (int)threadIdx.x;
    const int w    = __builtin_amdgcn_readfirstlane(tid >> 6);   // wave 0..7
    const int lane = tid & 63;
    const int m    = lane & 15;                                   // A row idx
    const int quad = lane >> 4;
    const int mq   = lane & 7;
    const int t0   = (int)blockIdx.x * TOKB;

    if (tid < NEXPERT) hist[tid] = 0;

    // staging: inst i covers rows i*8+(lane>>3); lane stores 16B at phys group
    // (lane&7); source group = (lane&7) ^ (row&7)  (row&7 == lane>>3)
    const int swz = (((lane & 7) ^ (lane >> 3)) << 2);
    // B source: ks = w*8 + s
    const unsigned short* wq = wf + (size_t)(w * 8) * 4096 + (size_t)lane * 8;

    v4f acc[4][4];                                    // [tile][nt]
#pragma unroll
    for (int t = 0; t < 4; ++t)
#pragma unroll
        for (int nt = 0; nt < 4; ++nt) acc[t][nt] = (v4f)0.f;
    float ss[4] = {0.f, 0.f, 0.f, 0.f};

    v8h bhA[4], blA[4], bhB[4], blB[4];

    // ---- prologue: stage chunk 0, load B(0) into set A, pin issue order
#pragma unroll
    for (int i = 0; i < 8; ++i) {
        const float* gp = h + (size_t)(t0 + i * 8 + (lane >> 3)) * HIDDEN
                        + w * 256 + swz;
        __builtin_amdgcn_global_load_lds(
            (const __attribute__((address_space(1))) void*)gp,
            (__attribute__((address_space(3))) void*)(stage + w * 4096 + i * 256),
            16, 0, 0);
    }
#pragma unroll
    for (int nt = 0; nt < 4; ++nt) {
        bhA[nt] = *(const v8h*)(wq + nt * 1024);
        blA[nt] = *(const v8h*)(wq + nt * 1024 + 512);
    }
    __builtin_amdgcn_sched_barrier(0);

#define ROUTER_STEP(S, CH, CL, NH, NL)                                        \
    {                                                                          \
        if ((S) < 7) {                                                         \
            float* dst = stage + w * 4096 + (((S) + 1) & 1) * 2048;            \
            _Pragma("unroll")                                                  \
            for (int i = 0; i < 8; ++i) {                                      \
                const float* gp = h + (size_t)(t0 + i * 8 + (lane >> 3)) * HIDDEN \
                                + w * 256 + ((S) + 1) * 32 + swz;              \
                __builtin_amdgcn_global_load_lds(                              \
                    (const __attribute__((address_space(1))) void*)gp,         \
                    (__attribute__((address_space(3))) void*)(dst + i * 256),  \
                    16, 0, 0);                                                 \
            }                                                                  \
        }                                                                      \
        __builtin_amdgcn_sched_barrier(0);                                     \
        if ((S) < 7) {                                                         \
            const unsigned short* bq = wq + (size_t)((S) + 1) * 4096;          \
            _Pragma("unroll")                                                  \
            for (int nt = 0; nt < 4; ++nt) {                                   \
                NH[nt] = *(const v8h*)(bq + nt * 1024);                        \
                NL[nt] = *(const v8h*)(bq + nt * 1024 + 512);                  \
            }                                                                  \
        }                                                                      \
        __builtin_amdgcn_sched_barrier(0);                                     \
        if ((S) < 7) asm volatile("s_waitcnt vmcnt(16)" ::: "memory");         \
        else         asm volatile("s_waitcnt vmcnt(0)"  ::: "memory");         \
        __builtin_amdgcn_sched_barrier(0);                                     \
        const float* chunk = stage + w * 4096 + ((S) & 1) * 2048;              \
        _Pragma("unroll")                                                      \
        for (int t = 0; t < 4; ++t) {                                          \
            const float* rb = chunk + (t * 16 + m) * 32;                       \
            float4 va = *(const float4*)(rb + (((quad * 2) ^ mq) << 2));       \
            float4 vb = *(const float4*)(rb + (((quad * 2 + 1) ^ mq) << 2));   \
            v8h ah, al;                                                        \
            cvt8(va, vb, ah, al, ss[t]);                                       \
            _Pragma("unroll")                                                  \
            for (int nt = 0; nt < 4; ++nt) {                                   \
                acc[t][nt] = __builtin_amdgcn_mfma_f32_16x16x32_f16(ah, CH[nt], acc[t][nt], 0, 0, 0); \
                acc[t][nt] = __builtin_amdgcn_mfma_f32_16x16x32_f16(ah, CL[nt], acc[t][nt], 0, 0, 0); \
                acc[t][nt] = __builtin_amdgcn_mfma_f32_16x16x32_f16(al, CH[nt], acc[t][nt], 0, 0, 0); \
            }                                                                  \
        }                                                                      \
    }

    ROUTER_STEP(0, bhA, blA, bhB, blB)
    ROUTER_STEP(1, bhB, blB, bhA, blA)
    ROUTER_STEP(2, bhA, blA, bhB, blB)
    ROUTER_STEP(3, bhB, blB, bhA, blA)
    ROUTER_STEP(4, bhA, blA, bhB, blB)
    ROUTER_STEP(5, bhB, blB, bhA, blA)
    ROUTER_STEP(6, bhA, blA, bhB, blB)
    ROUTER_STEP(7, bhB, blB, bhA, blA)
#undef ROUTER_STEP

    // ---- sum of squares: lane holds quad's 64-float share of rows t*16+m
#pragma unroll
    for (int t = 0; t < 4; ++t) {
        float s = ss[t];
        s += __shfl_xor(s, 16, 64);
        s += __shfl_xor(s, 32, 64);
        if (lane < 16) lss[w * 64 + t * 16 + lane] = s;
    }
    __syncthreads();   // all waves done reading stage -> lg alias safe

    // ---- raw logit partials: D row=(quad*4+reg)=token-in-tile, col=nt*16+m
#pragma unroll
    for (int t = 0; t < 4; ++t)
#pragma unroll
        for (int nt = 0; nt < 4; ++nt)
#pragma unroll
            for (int r = 0; r < 4; ++r)
                lg[(w * 64 + t * 16 + quad * 4 + r) * 66 + nt * 16 + m] = acc[t][nt][r];
    __syncthreads();

    // ---- top-8 epilogue (R0-verified): wave w handles tokens w*8..w*8+7
    for (int i = 0; i < 8; ++i) {
        const int tok = w * 8 + i;
        float l0 = lg[(0 * 64 + tok) * 66 + lane], l1 = lg[(1 * 64 + tok) * 66 + lane];
        float l2 = lg[(2 * 64 + tok) * 66 + lane], l3 = lg[(3 * 64 + tok) * 66 + lane];
        float l4 = lg[(4 * 64 + tok) * 66 + lane], l5 = lg[(5 * 64 + tok) * 66 + lane];
        float l6 = lg[(6 * 64 + tok) * 66 + lane], l7 = lg[(7 * 64 + tok) * 66 + lane];
        float lsum = ((l0 + l1) + (l2 + l3)) + ((l4 + l5) + (l6 + l7));
        float q01 = lss[0 * 64 + tok] + lss[1 * 64 + tok];
        float q23 = lss[2 * 64 + tok] + lss[3 * 64 + tok];
        float q45 = lss[4 * 64 + tok] + lss[5 * 64 + tok];
        float q67 = lss[6 * 64 + tok] + lss[7 * 64 + tok];
        double sst = (double)((q01 + q23) + (q45 + q67));
        double rr  = 1.0 / sqrt(sst * (1.0 / (double)HIDDEN) + 1e-6);
        float logit = (float)((double)lsum * rr * (RSQRT_H / (double)WSCALE));

        float work = logit;
        float myval = 0.f; int myidx = 0; float m0 = 0.f;
#pragma unroll
        for (int j = 0; j < TOPK; ++j) {
            float mx = work;
#pragma unroll
            for (int off = 32; off; off >>= 1) mx = fmaxf(mx, __shfl_xor(mx, off, 64));
            unsigned long long msk = __ballot(work == mx);
            int src = __ffsll((long long)msk) - 1;   // ties -> lowest index (jax)
            if (j == 0) m0 = mx;
            if (lane == j) { myval = mx; myidx = src; }
            if (lane == src) work = -3.402823466e38f;
        }

        float ev = (lane < TOPK) ? expf(myval - m0) : 0.f;
        float es = ev;
        es += __shfl_xor(es, 1, 64);
        es += __shfl_xor(es, 2, 64);
        es += __shfl_xor(es, 4, 64);
        if (lane < TOPK) {
            float wgt = (ev / es) * pes[myidx];
            size_t o = (size_t)(t0 + tok) * TOPK + lane;
            out_w[o] = wgt;
            out_i[o] = (float)myidx;                 // d_out read as float32
            atomicAdd(&hist[myidx], 1);
        }
    }

    __syncthreads();
    if (tid < NEXPERT)
        atomicAdd(&out_c[tid], (float)hist[tid]);    // counts are exact small ints
}

extern "C" void kernel_launch(void* const* d_in, const int* in_sizes, int n_in,
                              void* d_out, int out_size, void* d_ws, size_t ws_size,
                              hipStream_t stream) {
    const float* h     = (const float*)d_in[0];   // [4,4096,2048] f32
    const float* scale = (const float*)d_in[1];   // [2048] f32
    const float* w     = (const float*)d_in[2];   // [64,2048] f32
    const float* pes   = (const float*)d_in[3];   // [64] f32

    unsigned short* wf = (unsigned short*)d_ws;   // 512 KB f16 fragment bank

    float* out_w = (float*)d_out;                                  // [16384,8]
    float* out_i = (float*)d_out + (size_t)NTOK * TOPK;            // [16384,8] idx-as-f32
    float* out_c = (float*)d_out + (size_t)NTOK * TOPK * 2;        // [64]

    prep_wf<<<512, 256, 0, stream>>>(w, scale, wf, out_c);

    // 256 blocks x 512 thr (8 waves); exactly 1 block/CU
    router_main<<<NTOK / TOKB, 512, 0, stream>>>(h, wf, pes, out_w, out_i, out_c);
}

// Round 7
// 226.398 us; speedup vs baseline: 1.0610x; 1.0610x over previous
//
#include <hip/hip_runtime.h>
#include <math.h>

#define HIDDEN   2048
#define NEXPERT  64
#define TOPK     8
#define NTOK     16384
#define TOKB     16          // tokens per block (one 16-row M tile)
#define RSQRT_H  0.02209708691207961
#define WSCALE   64.0f       // keeps f16 Wl split in normal range; undone in epilogue

typedef __attribute__((ext_vector_type(8))) _Float16       v8h;
typedef __attribute__((ext_vector_type(8))) unsigned short v8u;
typedef __attribute__((ext_vector_type(4))) float          v4f;

static __device__ __forceinline__ unsigned short f16b(float x) {
    return __builtin_bit_cast(unsigned short, (_Float16)x);   // v_cvt_f16_f32 (RNE)
}
static __device__ __forceinline__ float f16f(unsigned short u) {
    return (float)__builtin_bit_cast(_Float16, u);
}

// Weight prep into B-fragment order: wf[ks(64)][nt(4)][hl(2)][lane(64)][j(8)] f16.
// B[k][n]: n = nt*16 + (lane&15), k = ks*32 + (lane>>4)*8 + j.  v = w*scale*64.
// Also zeroes out_c (replaces a separate hipMemsetAsync dispatch).
__global__ __launch_bounds__(256) void prep_wf(
    const float* __restrict__ w, const float* __restrict__ scale,
    unsigned short* __restrict__ wf, float* __restrict__ out_c)
{
    int i    = blockIdx.x * 256 + threadIdx.x;   // 131072
    if (i < NEXPERT) out_c[i] = 0.f;
    int j    = i & 7;
    int lane = (i >> 3) & 63;
    int nt   = (i >> 9) & 3;
    int ks   = i >> 11;
    int e    = nt * 16 + (lane & 15);
    int k    = ks * 32 + (lane >> 4) * 8 + j;
    float v  = w[e * HIDDEN + k] * scale[k] * WSCALE;
    unsigned short vh = f16b(v);
    unsigned short vl = f16b(v - f16f(vh));      // Dekker split: v - hi exact in f32
    size_t base = (((size_t)(ks * 4 + nt) * 2) * 64 + lane) * 8 + j;
    wf[base]       = vh;                          // hl=0
    wf[base + 512] = vl;                          // hl=1 (stride 64*8)
}

// Convert 8 f32 -> split-f16 hi/lo fragments; accumulate sum of squares.
static __device__ __forceinline__ void cvt8(
    float4 a, float4 b, v8h& ah, v8h& al, float& ss)
{
    float vv[8] = {a.x, a.y, a.z, a.w, b.x, b.y, b.z, b.w};
    v8u uh, ul;
#pragma unroll
    for (int j = 0; j < 8; ++j) {
        float v = vv[j];
        unsigned short hh = f16b(v);
        uh[j] = hh;
        ul[j] = f16b(v - f16f(hh));   // exact residual in f32, then RNE
        ss    = fmaf(v, v, ss);
    }
    ah = __builtin_bit_cast(v8h, uh);
    al = __builtin_bit_cast(v8h, ul);
}

// 16 tokens/block, 256 thr (4 waves), 1024 blocks. Wave w owns k-range
// [w*512, w*512+512) -> 16 k-steps of 32 (R2's verified partition; logits
// bit-identical). R3's proven schedule (batched B+X issue behind one
// sched_barrier, depth-1 X register prefetch) at a register footprint that
// cannot spill: acc 16 + B 32 + X 32 + temps ~= 95 < 128 cap, so we keep
// 16 waves/CU occupancy (R3's) with ZERO scratch traffic (R4-R6 lost
// 35 us to 48 MB spill at TOKB=64).
__global__ __launch_bounds__(256, 4) void router_main(
    const float* __restrict__ h, const unsigned short* __restrict__ wf,
    const float* __restrict__ pes,
    float* __restrict__ out_w, float* __restrict__ out_i, float* __restrict__ out_c)
{
    __shared__ __align__(16) float lg[4 * 16 * 65];   // [wave][token][expert+pad]
    __shared__ float lss[4 * 16];                     // [wave][token] partial sumsq
    __shared__ int   hist[NEXPERT];

    const int tid  = (int)threadIdx.x;
    const int w    = __builtin_amdgcn_readfirstlane(tid >> 6);   // wave 0..3
    const int lane = tid & 63;
    const int m    = lane & 15;                                   // A row / D col idx
    const int quad = lane >> 4;
    const int t0   = (int)blockIdx.x * TOKB;

    if (tid < NEXPERT) hist[tid] = 0;

    // A source: row (t0+m), k = w*512 + s*32 + quad*8 + j
    const float* xp = h + (size_t)(t0 + m) * HIDDEN + w * 512 + quad * 8;
    // B source: ks = w*16 + s; frag base = ks*4096 + nt*1024 (+512 for lo)
    const unsigned short* wq = wf + (size_t)(w * 16) * 4096 + (size_t)lane * 8;

    v4f acc[4];
#pragma unroll
    for (int nt = 0; nt < 4; ++nt) acc[nt] = (v4f)0.f;
    float ss = 0.f;

    float4 xa = *(const float4*)xp;
    float4 xb = *(const float4*)(xp + 4);

#pragma unroll
    for (int s = 0; s < 16; ++s) {
        // ---- issue ALL memory for this step first (8 B-frags + next X), fence
        const unsigned short* bq = wq + (size_t)s * 4096;
        v8h bh[4], bl[4];
#pragma unroll
        for (int nt = 0; nt < 4; ++nt) {
            bh[nt] = *(const v8h*)(bq + nt * 1024);
            bl[nt] = *(const v8h*)(bq + nt * 1024 + 512);
        }
        float4 na, nb;
        if (s < 15) {
            na = *(const float4*)(xp + (s + 1) * 32);
            nb = *(const float4*)(xp + (s + 1) * 32 + 4);
        }
        __builtin_amdgcn_sched_barrier(0);   // loads above, consumers below

        // ---- convert current X (overlaps B-load latency), 12 MFMAs
        v8h ah, al;
        cvt8(xa, xb, ah, al, ss);
#pragma unroll
        for (int nt = 0; nt < 4; ++nt) {
            acc[nt] = __builtin_amdgcn_mfma_f32_16x16x32_f16(ah, bh[nt], acc[nt], 0, 0, 0);
            acc[nt] = __builtin_amdgcn_mfma_f32_16x16x32_f16(ah, bl[nt], acc[nt], 0, 0, 0);
            acc[nt] = __builtin_amdgcn_mfma_f32_16x16x32_f16(al, bh[nt], acc[nt], 0, 0, 0);
        }

        if (s < 15) { xa = na; xb = nb; }
    }

    // ---- sum of squares: lane holds quad's 128-float share of row m
    {
        float s = ss;
        s += __shfl_xor(s, 16, 64);
        s += __shfl_xor(s, 32, 64);
        if (lane < 16) lss[w * 16 + lane] = s;
    }

    // ---- raw logit partials: D row=(quad*4+reg)=token, col=nt*16+m
#pragma unroll
    for (int nt = 0; nt < 4; ++nt)
#pragma unroll
        for (int r = 0; r < 4; ++r)
            lg[(w * 16 + quad * 4 + r) * 65 + nt * 16 + m] = acc[nt][r];
    __syncthreads();

    // ---- top-8 epilogue (R0/R2-verified): wave w handles tokens w*4..w*4+3
    for (int i = 0; i < 4; ++i) {
        const int tok = w * 4 + i;
        float lsum = (lg[tok * 65 + lane]        + lg[1040 + tok * 65 + lane])
                   + (lg[2080 + tok * 65 + lane] + lg[3120 + tok * 65 + lane]);
        float sst4 = (lss[tok] + lss[16 + tok]) + (lss[32 + tok] + lss[48 + tok]);
        double sst = (double)sst4;
        double rr  = 1.0 / sqrt(sst * (1.0 / (double)HIDDEN) + 1e-6);
        float logit = (float)((double)lsum * rr * (RSQRT_H / (double)WSCALE));

        float work = logit;
        float myval = 0.f; int myidx = 0; float m0 = 0.f;
#pragma unroll
        for (int j = 0; j < TOPK; ++j) {
            float mx = work;
#pragma unroll
            for (int off = 32; off; off >>= 1) mx = fmaxf(mx, __shfl_xor(mx, off, 64));
            unsigned long long msk = __ballot(work == mx);
            int src = __ffsll((long long)msk) - 1;   // ties -> lowest index (jax)
            if (j == 0) m0 = mx;
            if (lane == j) { myval = mx; myidx = src; }
            if (lane == src) work = -3.402823466e38f;
        }

        float ev = (lane < TOPK) ? expf(myval - m0) : 0.f;
        float es = ev;
        es += __shfl_xor(es, 1, 64);
        es += __shfl_xor(es, 2, 64);
        es += __shfl_xor(es, 4, 64);
        if (lane < TOPK) {
            float wgt = (ev / es) * pes[myidx];
            size_t o = (size_t)(t0 + tok) * TOPK + lane;
            out_w[o] = wgt;
            out_i[o] = (float)myidx;                 // d_out read as float32
            atomicAdd(&hist[myidx], 1);
        }
    }

    __syncthreads();
    if (tid < NEXPERT)
        atomicAdd(&out_c[tid], (float)hist[tid]);    // counts are exact small ints
}

extern "C" void kernel_launch(void* const* d_in, const int* in_sizes, int n_in,
                              void* d_out, int out_size, void* d_ws, size_t ws_size,
                              hipStream_t stream) {
    const float* h     = (const float*)d_in[0];   // [4,4096,2048] f32
    const float* scale = (const float*)d_in[1];   // [2048] f32
    const float* w     = (const float*)d_in[2];   // [64,2048] f32
    const float* pes   = (const float*)d_in[3];   // [64] f32

    unsigned short* wf = (unsigned short*)d_ws;   // 512 KB f16 fragment bank

    float* out_w = (float*)d_out;                                  // [16384,8]
    float* out_i = (float*)d_out + (size_t)NTOK * TOPK;            // [16384,8] idx-as-f32
    float* out_c = (float*)d_out + (size_t)NTOK * TOPK * 2;        // [64]

    prep_wf<<<512, 256, 0, stream>>>(w, scale, wf, out_c);

    // 1024 blocks x 256 thr (4 waves); target 4 blocks/CU, 16 waves/CU
    router_main<<<NTOK / TOKB, 256, 0, stream>>>(h, wf, pes, out_w, out_i, out_c);
}

// Round 8
// 221.172 us; speedup vs baseline: 1.0860x; 1.0236x over previous
//
#include <hip/hip_runtime.h>
#include <math.h>

#define HIDDEN   2048
#define NEXPERT  64
#define TOPK     8
#define NTOK     16384
#define TOKB     32          // tokens per block (two 16-row M tiles)
#define RSQRT_H  0.02209708691207961
#define WSCALE   64.0f       // keeps f16 Wl split in normal range; undone in epilogue

typedef __attribute__((ext_vector_type(8))) _Float16       v8h;
typedef __attribute__((ext_vector_type(8))) unsigned short v8u;
typedef __attribute__((ext_vector_type(4))) float          v4f;

static __device__ __forceinline__ unsigned short f16b(float x) {
    return __builtin_bit_cast(unsigned short, (_Float16)x);   // v_cvt_f16_f32 (RNE)
}
static __device__ __forceinline__ float f16f(unsigned short u) {
    return (float)__builtin_bit_cast(_Float16, u);
}

// Weight prep into B-fragment order: wf[ks(64)][nt(4)][hl(2)][lane(64)][j(8)] f16.
// B[k][n]: n = nt*16 + (lane&15), k = ks*32 + (lane>>4)*8 + j.  v = w*scale*64.
// Also zeroes out_c (replaces a separate hipMemsetAsync dispatch).
__global__ __launch_bounds__(256) void prep_wf(
    const float* __restrict__ w, const float* __restrict__ scale,
    unsigned short* __restrict__ wf, float* __restrict__ out_c)
{
    int i    = blockIdx.x * 256 + threadIdx.x;   // 131072
    if (i < NEXPERT) out_c[i] = 0.f;
    int j    = i & 7;
    int lane = (i >> 3) & 63;
    int nt   = (i >> 9) & 3;
    int ks   = i >> 11;
    int e    = nt * 16 + (lane & 15);
    int k    = ks * 32 + (lane >> 4) * 8 + j;
    float v  = w[e * HIDDEN + k] * scale[k] * WSCALE;
    unsigned short vh = f16b(v);
    unsigned short vl = f16b(v - f16f(vh));      // Dekker split: v - hi exact in f32
    size_t base = (((size_t)(ks * 4 + nt) * 2) * 64 + lane) * 8 + j;
    wf[base]       = vh;                          // hl=0
    wf[base + 512] = vl;                          // hl=1 (stride 64*8)
}

// Convert 8 f32 -> split-f16 hi/lo fragments; accumulate sum of squares.
static __device__ __forceinline__ void cvt8(
    v4f a, v4f b, v8h& ah, v8h& al, float& ss)
{
    float vv[8] = {a[0], a[1], a[2], a[3], b[0], b[1], b[2], b[3]};
    v8u uh, ul;
#pragma unroll
    for (int j = 0; j < 8; ++j) {
        float v = vv[j];
        unsigned short hh = f16b(v);
        uh[j] = hh;
        ul[j] = f16b(v - f16f(hh));   // exact residual in f32, then RNE
        ss    = fmaf(v, v, ss);
    }
    ah = __builtin_bit_cast(v8h, uh);
    al = __builtin_bit_cast(v8h, ul);
}

// 32 tokens/block, 256 thr (4 waves), 512 blocks. Wave w owns k-range
// [w*512, w*512+512) for BOTH 16-row M tiles -> wf re-read traffic halves
// vs TOKB=16 (512->256 MB), each batched B-group feeds 24 MFMAs.
// Diagnosis R0/R7: two disjoint schedules both delivered ~7.5 TB/s aggregate
// -> L3-BW bound, dominated by wf re-reads (X streaming evicts wf from L2).
// Fixes here: (1) TOKB=32 halves wf traffic at a provably non-spilling
// register footprint (~85 arch + 32 AGPR acc); (2) X loads are NON-TEMPORAL
// (nt bit) so the stream-once X no longer evicts wf from L2/L3 -> wf
// re-reads become cache-resident. X then comes from HBM (134 MB @ 6.3 TB/s
// = 21 us chip-wide, cheap).
// logits_raw = Xh*Wh + Xh*Wl + Xl*Wh  (split-f16; partials and reduction
// tree bit-identical to R7 per token).
__global__ __launch_bounds__(256, 4) void router_main(
    const float* __restrict__ h, const unsigned short* __restrict__ wf,
    const float* __restrict__ pes,
    float* __restrict__ out_w, float* __restrict__ out_i, float* __restrict__ out_c)
{
    __shared__ __align__(16) float lg[4 * 32 * 66];   // [partial][token][expert+pad]
    __shared__ float lss[4 * 32];                     // [partial][token] sumsq
    __shared__ int   hist[NEXPERT];

    const int tid  = (int)threadIdx.x;
    const int w    = __builtin_amdgcn_readfirstlane(tid >> 6);   // wave 0..3
    const int lane = tid & 63;
    const int m    = lane & 15;                                   // A row idx
    const int quad = lane >> 4;
    const int t0   = (int)blockIdx.x * TOKB;

    if (tid < NEXPERT) hist[tid] = 0;

    // A sources: rows (t0+m) and (t0+16+m), k = w*512 + s*32 + quad*8 + j
    const float* xp0 = h + (size_t)(t0 + m) * HIDDEN + w * 512 + quad * 8;
    const float* xp1 = xp0 + (size_t)16 * HIDDEN;
    // B source: ks = w*16 + s; frag base = ks*4096 + nt*1024 (+512 for lo)
    const unsigned short* wq = wf + (size_t)(w * 16) * 4096 + (size_t)lane * 8;

    v4f acc0[4], acc1[4];
#pragma unroll
    for (int nt = 0; nt < 4; ++nt) { acc0[nt] = (v4f)0.f; acc1[nt] = (v4f)0.f; }
    float ss0 = 0.f, ss1 = 0.f;

    v4f xa0 = __builtin_nontemporal_load((const v4f*)xp0);
    v4f xb0 = __builtin_nontemporal_load((const v4f*)(xp0 + 4));
    v4f xa1 = __builtin_nontemporal_load((const v4f*)xp1);
    v4f xb1 = __builtin_nontemporal_load((const v4f*)(xp1 + 4));

#pragma unroll
    for (int s = 0; s < 16; ++s) {
        // ---- issue ALL memory for this step first (8 B-frags + 4 nt X), fence
        const unsigned short* bq = wq + (size_t)s * 4096;
        v8h bh[4], bl[4];
#pragma unroll
        for (int nt = 0; nt < 4; ++nt) {
            bh[nt] = *(const v8h*)(bq + nt * 1024);
            bl[nt] = *(const v8h*)(bq + nt * 1024 + 512);
        }
        v4f na0, nb0, na1, nb1;
        if (s < 15) {
            na0 = __builtin_nontemporal_load((const v4f*)(xp0 + (s + 1) * 32));
            nb0 = __builtin_nontemporal_load((const v4f*)(xp0 + (s + 1) * 32 + 4));
            na1 = __builtin_nontemporal_load((const v4f*)(xp1 + (s + 1) * 32));
            nb1 = __builtin_nontemporal_load((const v4f*)(xp1 + (s + 1) * 32 + 4));
        }
        __builtin_amdgcn_sched_barrier(0);   // loads above, consumers below

        // ---- tile 0: convert current X (overlaps load latency), 12 MFMAs
        {
            v8h ah, al;
            cvt8(xa0, xb0, ah, al, ss0);
#pragma unroll
            for (int nt = 0; nt < 4; ++nt) {
                acc0[nt] = __builtin_amdgcn_mfma_f32_16x16x32_f16(ah, bh[nt], acc0[nt], 0, 0, 0);
                acc0[nt] = __builtin_amdgcn_mfma_f32_16x16x32_f16(ah, bl[nt], acc0[nt], 0, 0, 0);
                acc0[nt] = __builtin_amdgcn_mfma_f32_16x16x32_f16(al, bh[nt], acc0[nt], 0, 0, 0);
            }
        }
        // ---- tile 1
        {
            v8h ah, al;
            cvt8(xa1, xb1, ah, al, ss1);
#pragma unroll
            for (int nt = 0; nt < 4; ++nt) {
                acc1[nt] = __builtin_amdgcn_mfma_f32_16x16x32_f16(ah, bh[nt], acc1[nt], 0, 0, 0);
                acc1[nt] = __builtin_amdgcn_mfma_f32_16x16x32_f16(ah, bl[nt], acc1[nt], 0, 0, 0);
                acc1[nt] = __builtin_amdgcn_mfma_f32_16x16x32_f16(al, bh[nt], acc1[nt], 0, 0, 0);
            }
        }

        if (s < 15) { xa0 = na0; xb0 = nb0; xa1 = na1; xb1 = nb1; }
    }

    // ---- sum of squares: lane holds quad's 128-float share of its rows
    {
        float s0 = ss0, s1 = ss1;
        s0 += __shfl_xor(s0, 16, 64); s0 += __shfl_xor(s0, 32, 64);
        s1 += __shfl_xor(s1, 16, 64); s1 += __shfl_xor(s1, 32, 64);
        if (lane < 16) {
            lss[w * 32 + lane]      = s0;
            lss[w * 32 + 16 + lane] = s1;
        }
    }

    // ---- raw logit partials: D row=(quad*4+reg)=token-in-tile, col=nt*16+m
#pragma unroll
    for (int nt = 0; nt < 4; ++nt)
#pragma unroll
        for (int r = 0; r < 4; ++r) {
            lg[(w * 32 + quad * 4 + r) * 66 + nt * 16 + m]      = acc0[nt][r];
            lg[(w * 32 + 16 + quad * 4 + r) * 66 + nt * 16 + m] = acc1[nt][r];
        }
    __syncthreads();

    // ---- top-8 epilogue (R0/R7-verified): wave w handles tokens w*8..w*8+7
    for (int i = 0; i < 8; ++i) {
        const int tok = w * 8 + i;
        float lsum = (lg[(0 * 32 + tok) * 66 + lane] + lg[(1 * 32 + tok) * 66 + lane])
                   + (lg[(2 * 32 + tok) * 66 + lane] + lg[(3 * 32 + tok) * 66 + lane]);
        float sst4 = (lss[tok] + lss[32 + tok]) + (lss[64 + tok] + lss[96 + tok]);
        double sst = (double)sst4;
        double rr  = 1.0 / sqrt(sst * (1.0 / (double)HIDDEN) + 1e-6);
        float logit = (float)((double)lsum * rr * (RSQRT_H / (double)WSCALE));

        float work = logit;
        float myval = 0.f; int myidx = 0; float m0 = 0.f;
#pragma unroll
        for (int j = 0; j < TOPK; ++j) {
            float mx = work;
#pragma unroll
            for (int off = 32; off; off >>= 1) mx = fmaxf(mx, __shfl_xor(mx, off, 64));
            unsigned long long msk = __ballot(work == mx);
            int src = __ffsll((long long)msk) - 1;   // ties -> lowest index (jax)
            if (j == 0) m0 = mx;
            if (lane == j) { myval = mx; myidx = src; }
            if (lane == src) work = -3.402823466e38f;
        }

        float ev = (lane < TOPK) ? expf(myval - m0) : 0.f;
        float es = ev;
        es += __shfl_xor(es, 1, 64);
        es += __shfl_xor(es, 2, 64);
        es += __shfl_xor(es, 4, 64);
        if (lane < TOPK) {
            float wgt = (ev / es) * pes[myidx];
            size_t o = (size_t)(t0 + tok) * TOPK + lane;
            out_w[o] = wgt;
            out_i[o] = (float)myidx;                 // d_out read as float32
            atomicAdd(&hist[myidx], 1);
        }
    }

    __syncthreads();
    if (tid < NEXPERT)
        atomicAdd(&out_c[tid], (float)hist[tid]);    // counts are exact small ints
}

extern "C" void kernel_launch(void* const* d_in, const int* in_sizes, int n_in,
                              void* d_out, int out_size, void* d_ws, size_t ws_size,
                              hipStream_t stream) {
    const float* h     = (const float*)d_in[0];   // [4,4096,2048] f32
    const float* scale = (const float*)d_in[1];   // [2048] f32
    const float* w     = (const float*)d_in[2];   // [64,2048] f32
    const float* pes   = (const float*)d_in[3];   // [64] f32

    unsigned short* wf = (unsigned short*)d_ws;   // 512 KB f16 fragment bank

    float* out_w = (float*)d_out;                                  // [16384,8]
    float* out_i = (float*)d_out + (size_t)NTOK * TOPK;            // [16384,8] idx-as-f32
    float* out_c = (float*)d_out + (size_t)NTOK * TOPK * 2;        // [64]

    prep_wf<<<512, 256, 0, stream>>>(w, scale, wf, out_c);

    // 512 blocks x 256 thr (4 waves); 2 blocks/CU resident, 8 waves/CU
    router_main<<<NTOK / TOKB, 256, 0, stream>>>(h, wf, pes, out_w, out_i, out_c);
}